// Round 7
// baseline (223.470 us; speedup 1.0000x reference)
//
#include <hip/hip_runtime.h>

typedef __attribute__((ext_vector_type(8))) short  short8;
typedef __attribute__((ext_vector_type(4))) float  floatx4;
typedef __attribute__((ext_vector_type(4))) int    intx4;

constexpr int DIN = 100;
constexpr int H   = 64;
constexpr int G   = 10;
constexpr int NH  = 5;
constexpr int MWG = 128;                 // rows per block (4 waves x 32 rows)
constexpr int HP  = 72;                  // hbuf pitch in halfwords

// fragment counts in ws: dW0 (K=128 padded) 16; dW1 8; dbW 2; W0 5h*8=40
constexpr int NF_DW0 = 16, NF_DW1 = 8, NF_DBW = 2;
constexpr int NF_LIN = NF_DW0 + NF_DW1 + NF_DBW;     // 26
constexpr int NF_TOT = NF_LIN + 40;                  // 66

__device__ __forceinline__ unsigned short f2bf_rne(float f) {
    union { float f; unsigned u; } v{f};
    unsigned r = v.u + 0x7FFF + ((v.u >> 16) & 1);   // RNE
    return (unsigned short)(r >> 16);
}

__device__ __forceinline__ short8 pack8(const float* f) {
    intx4 p;
    #pragma unroll
    for (int j = 0; j < 4; ++j) {
        unsigned a = __float_as_uint(f[2 * j])     + 0x8000u;
        unsigned b = __float_as_uint(f[2 * j + 1]) + 0x8000u;
        p[j] = (int)((b & 0xFFFF0000u) | (a >> 16));
    }
    union { intx4 i; short8 s; } u; u.i = p;
    return u.s;
}

__device__ __forceinline__ unsigned short f2bf_hu(float f) {
    return (unsigned short)((__float_as_uint(f) + 0x8000u) >> 16);
}

__device__ __forceinline__ short8 ldfrag(const unsigned short* __restrict__ ws,
                                         int f, int lane) {
    return *(const short8*)(ws + (size_t)(f * 64 + lane) * 8);
}

// ---- pack all weights as bf16 MFMA B-fragments into ws ----
__global__ __launch_bounds__(64) void pack_kernel(
    const float* __restrict__ dW0, const float* __restrict__ dW1,
    const float* __restrict__ dbW, const float* __restrict__ W0,
    unsigned short* __restrict__ ws)
{
    const int f = blockIdx.x;
    const int lane = threadIdx.x;
    const int q = lane >> 4, cl = lane & 15;
    float v[8];
    if (f < NF_DW0) {
        int c = f >> 2, g = f & 3;
        #pragma unroll
        for (int j = 0; j < 8; ++j) {
            int k = c * 32 + q * 8 + j, n = g * 16 + cl;
            v[j] = (k < DIN) ? dW0[k * H + n] : 0.0f;
        }
    } else if (f < NF_DW0 + NF_DW1) {
        int r = f - NF_DW0; int c = r >> 2, g = r & 3;
        #pragma unroll
        for (int j = 0; j < 8; ++j) {
            int k = c * 32 + q * 8 + j, n = g * 16 + cl;
            v[j] = dW1[k * H + n];
        }
    } else if (f < NF_LIN) {
        int c = f - (NF_DW0 + NF_DW1);
        #pragma unroll
        for (int j = 0; j < 8; ++j) {
            int k = c * 32 + q * 8 + j, n = cl;
            v[j] = (n <= G) ? dbW[k * (G + 1) + n] : 0.0f;
        }
    } else {
        int r = f - NF_LIN; int h = r >> 3; r &= 7; int c = r >> 2, g = r & 3;
        #pragma unroll
        for (int j = 0; j < 8; ++j) {
            int k = c * 32 + q * 8 + j, n = g * 16 + cl;
            v[j] = W0[(h * H + k) * H + n];
        }
    }
    short8 s;
    #pragma unroll
    for (int j = 0; j < 8; ++j) s[j] = (short)f2bf_rne(v[j]);
    *(short8*)(ws + (size_t)(f * 64 + lane) * 8) = s;
}

// ---- bucket scatter: per-block LDS histogram + 5 global atomics/block ----
__global__ __launch_bounds__(256) void scatter_kernel(
    const float* __restrict__ dosage, int* __restrict__ lists,
    unsigned* __restrict__ cursors, int Btot)
{
    __shared__ unsigned bcnt[NH], gbase[NH];
    const int tid = threadIdx.x;
    const int gid = blockIdx.x * 256 + tid;
    if (tid < NH) bcnt[tid] = 0;
    __syncthreads();
    const float t = dosage[gid];
    int bk = (int)floorf(t * (float)NH);
    bk = min(max(bk, 0), NH - 1);
    const unsigned rank = atomicAdd(&bcnt[bk], 1u);
    __syncthreads();
    if (tid < NH) gbase[tid] = atomicAdd(&cursors[tid], bcnt[tid]);
    __syncthreads();
    lists[(size_t)bk * Btot + gbase[bk] + rank] = gid;
}

// ---- bucketed main kernel: one head per block; rows gathered via lists ----
__global__ __launch_bounds__(256, 4) void drnet_bucket(
    const float* __restrict__ dosage, const float* __restrict__ x,
    const float* __restrict__ db0, const float* __restrict__ db1,
    const float* __restrict__ dbB,
    const float* __restrict__ tw0, const float* __restrict__ b0,
    const float* __restrict__ W1, const float* __restrict__ tw1,
    const float* __restrict__ b1,
    const unsigned short* __restrict__ wsfrag,
    const int* __restrict__ lists, const unsigned* __restrict__ cursors,
    float* __restrict__ outg, float* __restrict__ outq,
    int Btot, int TPB)
{
    const int h     = blockIdx.x / TPB;
    const int tile0 = (blockIdx.x % TPB) * MWG;
    const int count = (int)cursors[h];
    if (tile0 >= count) return;

    __shared__ unsigned short hbuf[MWG * HP];    // 18432 B, wave-private slices
    const int tid  = threadIdx.x;
    const int wave = tid >> 6, lane = tid & 63;
    const int q = lane >> 4, cl = lane & 15;
    const int wbase = tile0 + wave * 32;
    if (wbase >= count) return;                  // wave-uniform, no barriers used
    unsigned short* hb = hbuf + wave * 32 * HP;
    const int* mylist = lists + (size_t)h * Btot;

    // per-lane gathered row for positions wbase + mt*16 + cl
    int rowv[2];
    #pragma unroll
    for (int mt = 0; mt < 2; ++mt)
        rowv[mt] = mylist[min(wbase + mt * 16 + cl, count - 1)];

    // C-layout rows (positions 4q+r), validity, dosage
    int   crow[2][4];
    float t8[2][4];
    bool  val[2][4];
    #pragma unroll
    for (int mt = 0; mt < 2; ++mt)
        #pragma unroll
        for (int r = 0; r < 4; ++r) {
            crow[mt][r] = __shfl(rowv[mt], 20 * q + r);      // lane 16q + (4q+r)
            val[mt][r]  = (wbase + mt * 16 + 4 * q + r) < count;
            t8[mt][r]   = dosage[crow[mt][r]];
        }

    // ================= layer 1: h1 = relu(x @ dW0 + db0), mt-split =================
    #pragma unroll 1
    for (int mt = 0; mt < 2; ++mt) {
        short8 a1[4];
        const float* xr = x + (size_t)rowv[mt] * DIN;
        #pragma unroll
        for (int cch = 0; cch < 4; ++cch) {
            float f[8];
            if (cch < 3) {
                floatx4 u0 = *(const floatx4*)(xr + cch * 32 + q * 8);
                floatx4 u1 = *(const floatx4*)(xr + cch * 32 + q * 8 + 4);
                f[0]=u0.x; f[1]=u0.y; f[2]=u0.z; f[3]=u0.w;
                f[4]=u1.x; f[5]=u1.y; f[6]=u1.z; f[7]=u1.w;
            } else {
                if (q == 0) {
                    floatx4 u0 = *(const floatx4*)(xr + 96);
                    f[0]=u0.x; f[1]=u0.y; f[2]=u0.z; f[3]=u0.w;
                    f[4]=f[5]=f[6]=f[7]=0.0f;
                } else {
                    #pragma unroll
                    for (int j = 0; j < 8; ++j) f[j] = 0.0f;
                }
            }
            a1[cch] = pack8(f);
        }
        floatx4 acc[4];
        #pragma unroll
        for (int g = 0; g < 4; ++g) acc[g] = (floatx4)0.0f;
        #pragma unroll
        for (int cch = 0; cch < 4; ++cch)
            #pragma unroll
            for (int g = 0; g < 4; ++g) {
                short8 bf = ldfrag(wsfrag, cch * 4 + g, lane);
                acc[g] = __builtin_amdgcn_mfma_f32_16x16x32_bf16(a1[cch], bf, acc[g], 0, 0, 0);
            }
        #pragma unroll
        for (int g = 0; g < 4; ++g) {
            float bias = db0[g * 16 + cl];
            #pragma unroll
            for (int r = 0; r < 4; ++r)
                hb[(mt * 16 + 4 * q + r) * HP + g * 16 + cl] =
                    f2bf_hu(fmaxf(acc[g][r] + bias, 0.0f));
        }
    }

    // ================= layer 2: h2 = relu(h1 @ dW1 + db1), mt-split =================
    #pragma unroll 1
    for (int mt = 0; mt < 2; ++mt) {
        short8 a2[2];
        #pragma unroll
        for (int cch = 0; cch < 2; ++cch)
            a2[cch] = *(const short8*)(hb + (mt * 16 + cl) * HP + cch * 32 + q * 8);
        floatx4 acc[4];
        #pragma unroll
        for (int g = 0; g < 4; ++g) acc[g] = (floatx4)0.0f;
        #pragma unroll
        for (int cch = 0; cch < 2; ++cch)
            #pragma unroll
            for (int g = 0; g < 4; ++g) {
                short8 bf = ldfrag(wsfrag, NF_DW0 + cch * 4 + g, lane);
                acc[g] = __builtin_amdgcn_mfma_f32_16x16x32_bf16(a2[cch], bf, acc[g], 0, 0, 0);
            }
        #pragma unroll
        for (int g = 0; g < 4; ++g) {
            float bias = db1[g * 16 + cl];
            #pragma unroll
            for (int r = 0; r < 4; ++r)
                hb[(mt * 16 + 4 * q + r) * HP + g * 16 + cl] =
                    f2bf_hu(fmaxf(acc[g][r] + bias, 0.0f));
        }
    }

    // h2 A-fragments (reused by density + head)
    short8 af[2][2];
    #pragma unroll
    for (int mt = 0; mt < 2; ++mt)
        #pragma unroll
        for (int cch = 0; cch < 2; ++cch)
            af[mt][cch] = *(const short8*)(hb + (mt * 16 + cl) * HP + cch * 32 + q * 8);

    // ======= density: softmax(h2 @ dbW + dbB) + interp (no max-sub: logits tiny) =======
    {
        floatx4 accd[2];
        accd[0] = (floatx4)0.0f; accd[1] = (floatx4)0.0f;
        #pragma unroll
        for (int cch = 0; cch < 2; ++cch) {
            short8 bf = ldfrag(wsfrag, NF_DW0 + NF_DW1 + cch, lane);
            #pragma unroll
            for (int mt = 0; mt < 2; ++mt)
                accd[mt] = __builtin_amdgcn_mfma_f32_16x16x32_bf16(af[mt][cch], bf, accd[mt], 0, 0, 0);
        }
        const float dbBv = (cl <= G) ? dbB[cl] : 0.0f;
        #pragma unroll
        for (int mt = 0; mt < 2; ++mt) {
            #pragma unroll
            for (int r = 0; r < 4; ++r) {
                float e = (cl <= G) ? __expf(accd[mt][r] + dbBv) : 0.0f;
                float s = e;
                s += __shfl_xor(s, 1); s += __shfl_xor(s, 2);
                s += __shfl_xor(s, 4); s += __shfl_xor(s, 8);
                const float t  = t8[mt][r];
                const float tB = t * (float)G;
                const float U  = ceilf(tB);
                const float inter = 1.0f - (U - tB);
                int Ui = (int)U; int Li = Ui - 1; if (Li < 0) Li = 0;
                float pL = __shfl(e, q * 16 + Li);
                float pU = __shfl(e, q * 16 + Ui);
                float gv = (pL + (pU - pL) * inter) / s;
                if (cl == 0 && val[mt][r]) outg[crow[mt][r]] = gv;
            }
        }
    }

    // ================= single head h: out = relu(h2@W0[h] + t*tw0 + b0) . W1[h] =================
    {
        floatx4 acch[2][4];
        #pragma unroll
        for (int mt = 0; mt < 2; ++mt)
            #pragma unroll
            for (int g = 0; g < 4; ++g) acch[mt][g] = (floatx4)0.0f;
        #pragma unroll
        for (int cch = 0; cch < 2; ++cch)
            #pragma unroll
            for (int g = 0; g < 4; ++g) {
                short8 bf = ldfrag(wsfrag, NF_LIN + h * 8 + cch * 4 + g, lane);
                #pragma unroll
                for (int mt = 0; mt < 2; ++mt)
                    acch[mt][g] = __builtin_amdgcn_mfma_f32_16x16x32_bf16(af[mt][cch], bf, acch[mt][g], 0, 0, 0);
            }
        float qp[2][4] = {{0,0,0,0},{0,0,0,0}};
        #pragma unroll
        for (int g = 0; g < 4; ++g) {
            const int off = h * H + g * 16 + cl;
            const float tw0v = tw0[off], b0v = b0[off], w1v = W1[off];
            #pragma unroll
            for (int mt = 0; mt < 2; ++mt)
                #pragma unroll
                for (int r = 0; r < 4; ++r) {
                    float h0 = acch[mt][g][r] + t8[mt][r] * tw0v + b0v;
                    qp[mt][r] += fmaxf(h0, 0.0f) * w1v;
                }
        }
        const float tw1v = tw1[h], b1v = b1[h];
        #pragma unroll
        for (int mt = 0; mt < 2; ++mt)
            #pragma unroll
            for (int r = 0; r < 4; ++r) {
                float s = qp[mt][r];
                s += __shfl_xor(s, 1); s += __shfl_xor(s, 2);
                s += __shfl_xor(s, 4); s += __shfl_xor(s, 8);
                float qv = s + t8[mt][r] * tw1v + b1v;
                if (cl == 0 && val[mt][r]) outq[crow[mt][r]] = qv;
            }
    }
}

// ---- fallback (R6) kernel: all heads + predicated select; used if ws too small ----
__global__ __launch_bounds__(256, 4) void drnet_mfma(
    const float* __restrict__ dosage, const float* __restrict__ x,
    const float* __restrict__ db0, const float* __restrict__ db1,
    const float* __restrict__ dbB,
    const float* __restrict__ tw0, const float* __restrict__ b0,
    const float* __restrict__ W1, const float* __restrict__ tw1,
    const float* __restrict__ b1,
    const unsigned short* __restrict__ wsfrag,
    float* __restrict__ outg, float* __restrict__ outq)
{
    __shared__ unsigned short hbuf[MWG * HP];
    const int tid  = threadIdx.x;
    const int wave = tid >> 6, lane = tid & 63;
    const int q = lane >> 4, cl = lane & 15;
    const int rowbase = blockIdx.x * MWG + wave * 32;
    unsigned short* hb = hbuf + wave * 32 * HP;

    float t8[2][4];
    int   bk8[2][4];
    #pragma unroll
    for (int mt = 0; mt < 2; ++mt) {
        floatx4 tv = *(const floatx4*)(dosage + rowbase + mt * 16 + 4 * q);
        #pragma unroll
        for (int r = 0; r < 4; ++r) {
            float t = tv[r];
            t8[mt][r] = t;
            int bk = (int)floorf(t * (float)NH);
            bk8[mt][r] = min(max(bk, 0), NH - 1);
        }
    }
    #pragma unroll 1
    for (int mt = 0; mt < 2; ++mt) {
        short8 a1[4];
        const float* xr = x + (size_t)(rowbase + mt * 16 + cl) * DIN;
        #pragma unroll
        for (int cch = 0; cch < 4; ++cch) {
            float f[8];
            if (cch < 3) {
                floatx4 u0 = *(const floatx4*)(xr + cch * 32 + q * 8);
                floatx4 u1 = *(const floatx4*)(xr + cch * 32 + q * 8 + 4);
                f[0]=u0.x; f[1]=u0.y; f[2]=u0.z; f[3]=u0.w;
                f[4]=u1.x; f[5]=u1.y; f[6]=u1.z; f[7]=u1.w;
            } else {
                if (q == 0) {
                    floatx4 u0 = *(const floatx4*)(xr + 96);
                    f[0]=u0.x; f[1]=u0.y; f[2]=u0.z; f[3]=u0.w;
                    f[4]=f[5]=f[6]=f[7]=0.0f;
                } else {
                    #pragma unroll
                    for (int j = 0; j < 8; ++j) f[j] = 0.0f;
                }
            }
            a1[cch] = pack8(f);
        }
        floatx4 acc[4];
        #pragma unroll
        for (int g = 0; g < 4; ++g) acc[g] = (floatx4)0.0f;
        #pragma unroll
        for (int cch = 0; cch < 4; ++cch)
            #pragma unroll
            for (int g = 0; g < 4; ++g) {
                short8 bf = ldfrag(wsfrag, cch * 4 + g, lane);
                acc[g] = __builtin_amdgcn_mfma_f32_16x16x32_bf16(a1[cch], bf, acc[g], 0, 0, 0);
            }
        #pragma unroll
        for (int g = 0; g < 4; ++g) {
            float bias = db0[g * 16 + cl];
            #pragma unroll
            for (int r = 0; r < 4; ++r)
                hb[(mt * 16 + 4 * q + r) * HP + g * 16 + cl] =
                    f2bf_hu(fmaxf(acc[g][r] + bias, 0.0f));
        }
    }
    #pragma unroll 1
    for (int mt = 0; mt < 2; ++mt) {
        short8 a2[2];
        #pragma unroll
        for (int cch = 0; cch < 2; ++cch)
            a2[cch] = *(const short8*)(hb + (mt * 16 + cl) * HP + cch * 32 + q * 8);
        floatx4 acc[4];
        #pragma unroll
        for (int g = 0; g < 4; ++g) acc[g] = (floatx4)0.0f;
        #pragma unroll
        for (int cch = 0; cch < 2; ++cch)
            #pragma unroll
            for (int g = 0; g < 4; ++g) {
                short8 bf = ldfrag(wsfrag, NF_DW0 + cch * 4 + g, lane);
                acc[g] = __builtin_amdgcn_mfma_f32_16x16x32_bf16(a2[cch], bf, acc[g], 0, 0, 0);
            }
        #pragma unroll
        for (int g = 0; g < 4; ++g) {
            float bias = db1[g * 16 + cl];
            #pragma unroll
            for (int r = 0; r < 4; ++r)
                hb[(mt * 16 + 4 * q + r) * HP + g * 16 + cl] =
                    f2bf_hu(fmaxf(acc[g][r] + bias, 0.0f));
        }
    }
    short8 af[2][2];
    #pragma unroll
    for (int mt = 0; mt < 2; ++mt)
        #pragma unroll
        for (int cch = 0; cch < 2; ++cch)
            af[mt][cch] = *(const short8*)(hb + (mt * 16 + cl) * HP + cch * 32 + q * 8);
    {
        floatx4 accd[2];
        accd[0] = (floatx4)0.0f; accd[1] = (floatx4)0.0f;
        #pragma unroll
        for (int cch = 0; cch < 2; ++cch) {
            short8 bf = ldfrag(wsfrag, NF_DW0 + NF_DW1 + cch, lane);
            #pragma unroll
            for (int mt = 0; mt < 2; ++mt)
                accd[mt] = __builtin_amdgcn_mfma_f32_16x16x32_bf16(af[mt][cch], bf, accd[mt], 0, 0, 0);
        }
        const float dbBv = (cl <= G) ? dbB[cl] : 0.0f;
        #pragma unroll
        for (int mt = 0; mt < 2; ++mt) {
            float gout[4];
            #pragma unroll
            for (int r = 0; r < 4; ++r) {
                float e = (cl <= G) ? __expf(accd[mt][r] + dbBv) : 0.0f;
                float s = e;
                s += __shfl_xor(s, 1); s += __shfl_xor(s, 2);
                s += __shfl_xor(s, 4); s += __shfl_xor(s, 8);
                const float t  = t8[mt][r];
                const float tB = t * (float)G;
                const float U  = ceilf(tB);
                const float inter = 1.0f - (U - tB);
                int Ui = (int)U; int Li = Ui - 1; if (Li < 0) Li = 0;
                float pL = __shfl(e, q * 16 + Li);
                float pU = __shfl(e, q * 16 + Ui);
                gout[r] = (pL + (pU - pL) * inter) / s;
            }
            if (cl == 0) {
                floatx4 gv = { gout[0], gout[1], gout[2], gout[3] };
                *(floatx4*)(outg + rowbase + mt * 16 + 4 * q) = gv;
            }
        }
    }
    float qp[2][4] = {{0,0,0,0},{0,0,0,0}};
    #pragma unroll 1
    for (int h = 0; h < NH; ++h) {
        #pragma unroll
        for (int gh = 0; gh < 2; ++gh) {
            floatx4 acch[2][2];
            #pragma unroll
            for (int mt = 0; mt < 2; ++mt)
                #pragma unroll
                for (int g = 0; g < 2; ++g) acch[mt][g] = (floatx4)0.0f;
            #pragma unroll
            for (int cch = 0; cch < 2; ++cch)
                #pragma unroll
                for (int g = 0; g < 2; ++g) {
                    short8 bf = ldfrag(wsfrag, NF_LIN + h * 8 + cch * 4 + gh * 2 + g, lane);
                    #pragma unroll
                    for (int mt = 0; mt < 2; ++mt)
                        acch[mt][g] = __builtin_amdgcn_mfma_f32_16x16x32_bf16(af[mt][cch], bf, acch[mt][g], 0, 0, 0);
                }
            #pragma unroll
            for (int g = 0; g < 2; ++g) {
                const int off = h * H + (gh * 2 + g) * 16 + cl;
                const float tw0v = tw0[off], b0v = b0[off], w1v = W1[off];
                #pragma unroll
                for (int mt = 0; mt < 2; ++mt)
                    #pragma unroll
                    for (int r = 0; r < 4; ++r) {
                        float h0 = acch[mt][g][r] + t8[mt][r] * tw0v + b0v;
                        float c  = fmaxf(h0, 0.0f) * w1v;
                        qp[mt][r] += (bk8[mt][r] == h) ? c : 0.0f;
                    }
            }
        }
    }
    #pragma unroll
    for (int mt = 0; mt < 2; ++mt) {
        #pragma unroll
        for (int r = 0; r < 4; ++r) {
            float s = qp[mt][r];
            s += __shfl_xor(s, 1); s += __shfl_xor(s, 2);
            s += __shfl_xor(s, 4); s += __shfl_xor(s, 8);
            const int h = bk8[mt][r];
            qp[mt][r] = s + t8[mt][r] * tw1[h] + b1[h];
        }
        if (cl == 0) {
            floatx4 Qv = { qp[mt][0], qp[mt][1], qp[mt][2], qp[mt][3] };
            *(floatx4*)(outq + rowbase + mt * 16 + 4 * q) = Qv;
        }
    }
}

extern "C" void kernel_launch(void* const* d_in, const int* in_sizes, int n_in,
                              void* d_out, int out_size, void* d_ws, size_t ws_size,
                              hipStream_t stream) {
    const float* dosage = (const float*)d_in[0];
    const float* x      = (const float*)d_in[1];
    const float* dW0    = (const float*)d_in[2];
    const float* db0    = (const float*)d_in[3];
    const float* dW1    = (const float*)d_in[4];
    const float* db1    = (const float*)d_in[5];
    const float* dbW    = (const float*)d_in[6];
    const float* dbB    = (const float*)d_in[7];
    const float* W0     = (const float*)d_in[8];
    const float* tw0    = (const float*)d_in[9];
    const float* b0     = (const float*)d_in[10];
    const float* W1     = (const float*)d_in[11];
    const float* tw1    = (const float*)d_in[12];
    const float* b1     = (const float*)d_in[13];

    const int Btot = in_sizes[0];
    float* outg = (float*)d_out;
    float* outq = outg + Btot;

    // ws layout: [frags 67584 B][cursors 64 B][lists 5*Btot*4 B]
    unsigned short* wsfrag = (unsigned short*)d_ws;
    const size_t frag_bytes = (size_t)NF_TOT * 64 * 8 * 2;
    unsigned* cursors = (unsigned*)((char*)d_ws + frag_bytes);
    int* lists = (int*)((char*)d_ws + frag_bytes + 64);
    const size_t need = frag_bytes + 64 + (size_t)NH * Btot * 4;

    pack_kernel<<<NF_TOT, 64, 0, stream>>>(dW0, dW1, dbW, W0, wsfrag);

    if (ws_size >= need) {
        hipMemsetAsync(cursors, 0, NH * sizeof(unsigned), stream);
        scatter_kernel<<<Btot / 256, 256, 0, stream>>>(dosage, lists, cursors, Btot);
        const int TPB = Btot / MWG;               // tiles-of-128 per bucket
        drnet_bucket<<<NH * TPB, 256, 0, stream>>>(dosage, x, db0, db1, dbB,
                                                   tw0, b0, W1, tw1, b1,
                                                   wsfrag, lists, cursors,
                                                   outg, outq, Btot, TPB);
    } else {
        drnet_mfma<<<Btot / MWG, 256, 0, stream>>>(dosage, x, db0, db1, dbB,
                                                   tw0, b0, W1, tw1, b1,
                                                   wsfrag, outg, outq);
    }
}

// Round 8
// 209.879 us; speedup vs baseline: 1.0648x; 1.0648x over previous
//
#include <hip/hip_runtime.h>

typedef __attribute__((ext_vector_type(8))) short  short8;
typedef __attribute__((ext_vector_type(4))) float  floatx4;
typedef __attribute__((ext_vector_type(4))) int    intx4;

constexpr int DIN = 100;
constexpr int H   = 64;
constexpr int G   = 10;
constexpr int NH  = 5;
constexpr int MWG = 128;                 // rows per block (4 waves x 32 rows)
constexpr int HP  = 72;                  // hbuf pitch in halfwords

// fragment counts in ws: dW0 (K=128 padded) 16; dW1 8; dbW 2; W0 5h*8=40
constexpr int NF_DW0 = 16, NF_DW1 = 8, NF_DBW = 2;
constexpr int NF_LIN = NF_DW0 + NF_DW1 + NF_DBW;     // 26
constexpr int NF_TOT = NF_LIN + 40;                  // 66
// epi table: per head, 3 params (tw0,b0,W1), lane-transposed float4 [h][which][cl] -> (g0..g3)
constexpr int EPI_F4 = NH * 3 * 16;                  // 240 float4

__device__ __forceinline__ unsigned short f2bf_rne(float f) {
    union { float f; unsigned u; } v{f};
    unsigned r = v.u + 0x7FFF + ((v.u >> 16) & 1);   // RNE
    return (unsigned short)(r >> 16);
}

__device__ __forceinline__ short8 pack8(const float* f) {
    intx4 p;
    #pragma unroll
    for (int j = 0; j < 4; ++j) {
        unsigned a = __float_as_uint(f[2 * j])     + 0x8000u;
        unsigned b = __float_as_uint(f[2 * j + 1]) + 0x8000u;
        p[j] = (int)((b & 0xFFFF0000u) | (a >> 16));
    }
    union { intx4 i; short8 s; } u; u.i = p;
    return u.s;
}

__device__ __forceinline__ unsigned short f2bf_hu(float f) {
    return (unsigned short)((__float_as_uint(f) + 0x8000u) >> 16);
}

__device__ __forceinline__ short8 ldfrag(const unsigned short* __restrict__ ws,
                                         int f, int lane) {
    return *(const short8*)(ws + (size_t)(f * 64 + lane) * 8);
}

// ---- pack weights as bf16 MFMA B-fragments + epi float4 tables into ws ----
__global__ __launch_bounds__(64) void pack_kernel(
    const float* __restrict__ dW0, const float* __restrict__ dW1,
    const float* __restrict__ dbW, const float* __restrict__ W0,
    const float* __restrict__ tw0, const float* __restrict__ b0,
    const float* __restrict__ W1,
    unsigned short* __restrict__ ws, float* __restrict__ wsepi)
{
    const int f = blockIdx.x;
    const int lane = threadIdx.x;
    const int q = lane >> 4, cl = lane & 15;
    if (f == NF_TOT) {                   // epi tables
        for (int idx = lane; idx < EPI_F4; idx += 64) {
            const int h = idx / 48, rem = idx % 48;
            const int which = rem / 16, c = rem % 16;
            const float* src = (which == 0) ? tw0 : (which == 1) ? b0 : W1;
            float4 v;
            v.x = src[h * H + 0 * 16 + c];
            v.y = src[h * H + 1 * 16 + c];
            v.z = src[h * H + 2 * 16 + c];
            v.w = src[h * H + 3 * 16 + c];
            *(float4*)(wsepi + idx * 4) = v;
        }
        return;
    }
    float v[8];
    if (f < NF_DW0) {
        int c = f >> 2, g = f & 3;
        #pragma unroll
        for (int j = 0; j < 8; ++j) {
            int k = c * 32 + q * 8 + j, n = g * 16 + cl;
            v[j] = (k < DIN) ? dW0[k * H + n] : 0.0f;
        }
    } else if (f < NF_DW0 + NF_DW1) {
        int r = f - NF_DW0; int c = r >> 2, g = r & 3;
        #pragma unroll
        for (int j = 0; j < 8; ++j) {
            int k = c * 32 + q * 8 + j, n = g * 16 + cl;
            v[j] = dW1[k * H + n];
        }
    } else if (f < NF_LIN) {
        int c = f - (NF_DW0 + NF_DW1);
        #pragma unroll
        for (int j = 0; j < 8; ++j) {
            int k = c * 32 + q * 8 + j, n = cl;
            v[j] = (n <= G) ? dbW[k * (G + 1) + n] : 0.0f;
        }
    } else {
        int r = f - NF_LIN; int h = r >> 3; r &= 7; int c = r >> 2, g = r & 3;
        #pragma unroll
        for (int j = 0; j < 8; ++j) {
            int k = c * 32 + q * 8 + j, n = g * 16 + cl;
            v[j] = W0[(h * H + k) * H + n];
        }
    }
    short8 s;
    #pragma unroll
    for (int j = 0; j < 8; ++j) s[j] = (short)f2bf_rne(v[j]);
    *(short8*)(ws + (size_t)(f * 64 + lane) * 8) = s;
}

// ---- main kernel: LDS counting-sort per 128-row block -> near-bucket-uniform
//      waves; head stage runs only buckets present (wave-uniform mask) ----
__global__ __launch_bounds__(256, 4) void drnet_sorted(
    const float* __restrict__ dosage, const float* __restrict__ x,
    const float* __restrict__ db0, const float* __restrict__ db1,
    const float* __restrict__ dbB,
    const float* __restrict__ tw1, const float* __restrict__ b1,
    const unsigned short* __restrict__ wsfrag,
    const floatx4* __restrict__ wsepi,
    float* __restrict__ outg, float* __restrict__ outq)
{
    __shared__ unsigned short hbuf[MWG * HP];    // 18432 B, wave-private slices
    __shared__ int      perm[MWG];
    __shared__ unsigned scnt[8];
    __shared__ unsigned sbase[8];

    const int tid  = threadIdx.x;
    const int wave = tid >> 6, lane = tid & 63;
    const int q = lane >> 4, cl = lane & 15;
    const int rowbase = blockIdx.x * MWG;
    unsigned short* hb = hbuf + wave * 32 * HP;

    // ---- LDS counting sort of the block's 128 rows by bucket ----
    if (tid < 8) scnt[tid] = 0;
    __syncthreads();
    int mybk = 0; unsigned myrank = 0;
    if (tid < MWG) {
        float t = dosage[rowbase + tid];
        mybk = min(max((int)floorf(t * (float)NH), 0), NH - 1);
        myrank = atomicAdd(&scnt[mybk], 1u);
    }
    __syncthreads();
    if (tid == 0) {
        unsigned s = 0;
        #pragma unroll
        for (int h = 0; h < NH; ++h) { sbase[h] = s; s += scnt[h]; }
    }
    __syncthreads();
    if (tid < MWG) perm[sbase[mybk] + myrank] = tid;
    __syncthreads();

    // ---- per-lane sorted rows (A-layout positions wave*32 + mt*16 + cl) ----
    int li[2]; float tl[2]; int bkl[2];
    #pragma unroll
    for (int mt = 0; mt < 2; ++mt) {
        li[mt]  = perm[wave * 32 + mt * 16 + cl];
        tl[mt]  = dosage[rowbase + li[mt]];
        bkl[mt] = min(max((int)floorf(tl[mt] * (float)NH), 0), NH - 1);
    }
    // wave-uniform bucket mask (OR over 16 cl values; quads identical)
    unsigned mk = (1u << bkl[0]) | (1u << bkl[1]);
    mk |= __shfl_xor(mk, 1); mk |= __shfl_xor(mk, 2);
    mk |= __shfl_xor(mk, 4); mk |= __shfl_xor(mk, 8);
    const unsigned mku = (unsigned)__builtin_amdgcn_readfirstlane((int)mk);

    // C-layout row info (position 4q+r) via cross-lane pull
    int crow[2][4]; float t8[2][4]; int bk8[2][4];
    #pragma unroll
    for (int mt = 0; mt < 2; ++mt)
        #pragma unroll
        for (int r = 0; r < 4; ++r) {
            crow[mt][r] = __shfl(li[mt],  20 * q + r);
            t8[mt][r]   = __shfl(tl[mt],  20 * q + r);
            bk8[mt][r]  = __shfl(bkl[mt], 20 * q + r);
        }

    // ================= layer 1: h1 = relu(x @ dW0 + db0), mt-split =================
    #pragma unroll 1
    for (int mt = 0; mt < 2; ++mt) {
        short8 a1[4];
        const float* xr = x + (size_t)(rowbase + li[mt]) * DIN;
        #pragma unroll
        for (int cch = 0; cch < 4; ++cch) {
            float f[8];
            if (cch < 3) {
                floatx4 u0 = *(const floatx4*)(xr + cch * 32 + q * 8);
                floatx4 u1 = *(const floatx4*)(xr + cch * 32 + q * 8 + 4);
                f[0]=u0.x; f[1]=u0.y; f[2]=u0.z; f[3]=u0.w;
                f[4]=u1.x; f[5]=u1.y; f[6]=u1.z; f[7]=u1.w;
            } else {
                if (q == 0) {
                    floatx4 u0 = *(const floatx4*)(xr + 96);
                    f[0]=u0.x; f[1]=u0.y; f[2]=u0.z; f[3]=u0.w;
                    f[4]=f[5]=f[6]=f[7]=0.0f;
                } else {
                    #pragma unroll
                    for (int j = 0; j < 8; ++j) f[j] = 0.0f;
                }
            }
            a1[cch] = pack8(f);
        }
        floatx4 acc[4];
        #pragma unroll
        for (int g = 0; g < 4; ++g) acc[g] = (floatx4)0.0f;
        #pragma unroll
        for (int cch = 0; cch < 4; ++cch)
            #pragma unroll
            for (int g = 0; g < 4; ++g) {
                short8 bf = ldfrag(wsfrag, cch * 4 + g, lane);
                acc[g] = __builtin_amdgcn_mfma_f32_16x16x32_bf16(a1[cch], bf, acc[g], 0, 0, 0);
            }
        #pragma unroll
        for (int g = 0; g < 4; ++g) {
            float bias = db0[g * 16 + cl];
            #pragma unroll
            for (int r = 0; r < 4; ++r)
                hb[(mt * 16 + 4 * q + r) * HP + g * 16 + cl] =
                    f2bf_hu(fmaxf(acc[g][r] + bias, 0.0f));
        }
    }

    // ================= layer 2: h2 = relu(h1 @ dW1 + db1), mt-split =================
    #pragma unroll 1
    for (int mt = 0; mt < 2; ++mt) {
        short8 a2[2];
        #pragma unroll
        for (int cch = 0; cch < 2; ++cch)
            a2[cch] = *(const short8*)(hb + (mt * 16 + cl) * HP + cch * 32 + q * 8);
        floatx4 acc[4];
        #pragma unroll
        for (int g = 0; g < 4; ++g) acc[g] = (floatx4)0.0f;
        #pragma unroll
        for (int cch = 0; cch < 2; ++cch)
            #pragma unroll
            for (int g = 0; g < 4; ++g) {
                short8 bf = ldfrag(wsfrag, NF_DW0 + cch * 4 + g, lane);
                acc[g] = __builtin_amdgcn_mfma_f32_16x16x32_bf16(a2[cch], bf, acc[g], 0, 0, 0);
            }
        #pragma unroll
        for (int g = 0; g < 4; ++g) {
            float bias = db1[g * 16 + cl];
            #pragma unroll
            for (int r = 0; r < 4; ++r)
                hb[(mt * 16 + 4 * q + r) * HP + g * 16 + cl] =
                    f2bf_hu(fmaxf(acc[g][r] + bias, 0.0f));
        }
    }

    // h2 A-fragments (reused by density + heads)
    short8 af[2][2];
    #pragma unroll
    for (int mt = 0; mt < 2; ++mt)
        #pragma unroll
        for (int cch = 0; cch < 2; ++cch)
            af[mt][cch] = *(const short8*)(hb + (mt * 16 + cl) * HP + cch * 32 + q * 8);

    // ======= density: softmax(h2 @ dbW + dbB) + interp (no max-sub: logits tiny) =======
    {
        floatx4 accd[2];
        accd[0] = (floatx4)0.0f; accd[1] = (floatx4)0.0f;
        #pragma unroll
        for (int cch = 0; cch < 2; ++cch) {
            short8 bf = ldfrag(wsfrag, NF_DW0 + NF_DW1 + cch, lane);
            #pragma unroll
            for (int mt = 0; mt < 2; ++mt)
                accd[mt] = __builtin_amdgcn_mfma_f32_16x16x32_bf16(af[mt][cch], bf, accd[mt], 0, 0, 0);
        }
        const float dbBv = (cl <= G) ? dbB[cl] : 0.0f;
        #pragma unroll
        for (int mt = 0; mt < 2; ++mt)
            #pragma unroll
            for (int r = 0; r < 4; ++r) {
                float e = (cl <= G) ? __expf(accd[mt][r] + dbBv) : 0.0f;
                float s = e;
                s += __shfl_xor(s, 1); s += __shfl_xor(s, 2);
                s += __shfl_xor(s, 4); s += __shfl_xor(s, 8);
                const float t  = t8[mt][r];
                const float tB = t * (float)G;
                const float U  = ceilf(tB);
                const float inter = 1.0f - (U - tB);
                int Ui = (int)U; int Li = Ui - 1; if (Li < 0) Li = 0;
                float pL = __shfl(e, q * 16 + Li);
                float pU = __shfl(e, q * 16 + Ui);
                float gv = (pL + (pU - pL) * inter) / s;
                if (cl == 0) outg[rowbase + crow[mt][r]] = gv;
            }
    }

    // ===== heads: only buckets present in this wave (wave-uniform branch) =====
    float qp[2][4] = {{0,0,0,0},{0,0,0,0}};
    #pragma unroll 1
    for (int h = 0; h < NH; ++h) {
        if (!((mku >> h) & 1u)) continue;
        floatx4 acch[2][4];
        #pragma unroll
        for (int mt = 0; mt < 2; ++mt)
            #pragma unroll
            for (int g = 0; g < 4; ++g) acch[mt][g] = (floatx4)0.0f;
        #pragma unroll
        for (int cch = 0; cch < 2; ++cch)
            #pragma unroll
            for (int g = 0; g < 4; ++g) {
                short8 bf = ldfrag(wsfrag, NF_LIN + h * 8 + cch * 4 + g, lane);
                #pragma unroll
                for (int mt = 0; mt < 2; ++mt)
                    acch[mt][g] = __builtin_amdgcn_mfma_f32_16x16x32_bf16(af[mt][cch], bf, acch[mt][g], 0, 0, 0);
            }
        const floatx4 tw0v = wsepi[(h * 3 + 0) * 16 + cl];
        const floatx4 b0v  = wsepi[(h * 3 + 1) * 16 + cl];
        const floatx4 w1v  = wsepi[(h * 3 + 2) * 16 + cl];
        #pragma unroll
        for (int mt = 0; mt < 2; ++mt)
            #pragma unroll
            for (int r = 0; r < 4; ++r) {
                float s = 0.0f;
                #pragma unroll
                for (int g = 0; g < 4; ++g) {
                    float h0 = acch[mt][g][r] + t8[mt][r] * tw0v[g] + b0v[g];
                    s += fmaxf(h0, 0.0f) * w1v[g];
                }
                qp[mt][r] += (bk8[mt][r] == h) ? s : 0.0f;
            }
    }
    #pragma unroll
    for (int mt = 0; mt < 2; ++mt)
        #pragma unroll
        for (int r = 0; r < 4; ++r) {
            float s = qp[mt][r];
            s += __shfl_xor(s, 1); s += __shfl_xor(s, 2);
            s += __shfl_xor(s, 4); s += __shfl_xor(s, 8);
            const int h = bk8[mt][r];
            float qv = s + t8[mt][r] * tw1[h] + b1[h];
            if (cl == 0) outq[rowbase + crow[mt][r]] = qv;
        }
}

extern "C" void kernel_launch(void* const* d_in, const int* in_sizes, int n_in,
                              void* d_out, int out_size, void* d_ws, size_t ws_size,
                              hipStream_t stream) {
    const float* dosage = (const float*)d_in[0];
    const float* x      = (const float*)d_in[1];
    const float* dW0    = (const float*)d_in[2];
    const float* db0    = (const float*)d_in[3];
    const float* dW1    = (const float*)d_in[4];
    const float* db1    = (const float*)d_in[5];
    const float* dbW    = (const float*)d_in[6];
    const float* dbB    = (const float*)d_in[7];
    const float* W0     = (const float*)d_in[8];
    const float* tw0    = (const float*)d_in[9];
    const float* b0     = (const float*)d_in[10];
    const float* W1     = (const float*)d_in[11];
    const float* tw1    = (const float*)d_in[12];
    const float* b1     = (const float*)d_in[13];

    const int Btot = in_sizes[0];
    float* outg = (float*)d_out;
    float* outq = outg + Btot;

    // ws layout: [frags 67584 B][epi 3840 B]
    unsigned short* wsfrag = (unsigned short*)d_ws;
    const size_t frag_bytes = (size_t)NF_TOT * 64 * 8 * 2;
    float* wsepi = (float*)((char*)d_ws + frag_bytes);

    pack_kernel<<<NF_TOT + 1, 64, 0, stream>>>(dW0, dW1, dbW, W0, tw0, b0, W1,
                                               wsfrag, wsepi);
    drnet_sorted<<<Btot / MWG, 256, 0, stream>>>(dosage, x, db0, db1, dbB,
                                                 tw1, b1, wsfrag,
                                                 (const floatx4*)wsepi,
                                                 outg, outq);
}